// Round 12
// baseline (178.921 us; speedup 1.0000x reference)
//
#include <hip/hip_runtime.h>
#include <math.h>

#define SEQ 2048
#define VOCAB 2048
#define BATCH 8
#define NTRIL 136  // 16*17/2 lower-tri 128x128 tiles

typedef unsigned short u16;
typedef __attribute__((ext_vector_type(4))) float f32x4;
typedef __attribute__((ext_vector_type(8))) short bf16x8;

__device__ __forceinline__ u16 f2bf(float f) {
  unsigned int u = __builtin_bit_cast(unsigned int, f);
  u += 0x7fffu + ((u >> 16) & 1u);
  return (u16)(u >> 16);
}

__device__ __forceinline__ float b2f(u16 h) {
  unsigned int u = ((unsigned int)h) << 16;
  return __builtin_bit_cast(float, u);
}

__device__ __forceinline__ void async16(const void* g, void* l) {
  __builtin_amdgcn_global_load_lds((const __attribute__((address_space(1))) void*)g,
                                   (__attribute__((address_space(3))) void*)l, 16, 0, 0);
}

// ---------------- f32 -> bf16 convert (3 arrays) + zero-region, one launch ----------------
__global__ __launch_bounds__(256) void cvt_all(const float* __restrict__ pos, const float* __restrict__ WQ1,
                                               const float* __restrict__ WK1, u16* __restrict__ Pbf,
                                               u16* __restrict__ Wqk, float4* __restrict__ zreg, int nz4) {
  const int i = blockIdx.x * 256 + threadIdx.x;  // over SEQ*SEQ/4 float4s
  const int seg = blockIdx.y;
  if (seg == 3) {
    if (i < nz4) zreg[i] = make_float4(0.f, 0.f, 0.f, 0.f);
    return;
  }
  const float* src = (seg == 0) ? pos : (seg == 1) ? WQ1 : WK1;
  u16* dst = (seg == 0) ? Pbf : (seg == 1) ? Wqk : Wqk + (size_t)SEQ * SEQ;
  float4 v = ((const float4*)src)[i];
  ushort4 o;
  o.x = f2bf(v.x); o.y = f2bf(v.y); o.z = f2bf(v.z); o.w = f2bf(v.w);
  ((ushort4*)dst)[i] = o;
}

// ---------------- BK=32 helpers (gemm_s1): LDS [128][32] per buffer ----------------
// NOTE: gemm_s1 must stay at BK=32 / 32KB LDS — BK=64 (64KB) regressed ~30µs in R6
// (occupancy cliff: split-K grid needs >2 blocks/CU co-residency to hide stragglers).
// NOTE: cooperative-kernel tail fusion (R8) fails under graph capture — kernel never runs.
// NOTE: 4-rows-per-block balanced sm_apply (R9) regressed vs 2048-block longest-first.
// NOTE: max-free softmax is safe here: logits ~N(0,~1.5), max |logit| < 8 << 88 (f32 exp range).
__device__ __forceinline__ void stage_tile(const u16* __restrict__ A, const u16* __restrict__ B,
                                           u16* As, u16* Bs, int m0, int n0, int kt,
                                           int wid, int lane) {
  const int c0 = wid * 2;
  const int skel = (lane & 3) * 8;
#pragma unroll
  for (int r = 0; r < 2; ++r) {
    const int chunk = c0 + r;
    const int row = chunk * 16 + (lane >> 2);
    async16(A + (size_t)(m0 + row) * SEQ + kt + skel, As + chunk * 512);
    async16(B + (size_t)(n0 + row) * SEQ + kt + skel, Bs + chunk * 512);
  }
}

__device__ __forceinline__ void compute_tile(const u16* As, const u16* Bs, f32x4 acc[4][4],
                                             int wr, int wc, int frow, int fk) {
  bf16x8 af[4], bfv[4];
#pragma unroll
  for (int mi = 0; mi < 4; ++mi) af[mi] = *(const bf16x8*)&As[(wr * 64 + mi * 16 + frow) * 32 + fk];
#pragma unroll
  for (int ni = 0; ni < 4; ++ni) bfv[ni] = *(const bf16x8*)&Bs[(wc * 64 + ni * 16 + frow) * 32 + fk];
#pragma unroll
  for (int mi = 0; mi < 4; ++mi)
#pragma unroll
    for (int ni = 0; ni < 4; ++ni)
      acc[mi][ni] = __builtin_amdgcn_mfma_f32_16x16x32_bf16(af[mi], bfv[ni], acc[mi][ni], 0, 0, 0);
}

// ---------------- BK=64 helpers (gemm_qk): LDS [2][128][32] per buffer ----------------
__device__ __forceinline__ void stage64(const u16* __restrict__ A, const u16* __restrict__ B,
                                        u16* As, u16* Bs, int m0, int n0, int kt,
                                        int wid, int lane) {
  const int c0 = wid * 2;
  const int skel = (lane & 3) * 8;
#pragma unroll
  for (int r = 0; r < 2; ++r) {
    const int chunk = c0 + r;
    const int row = chunk * 16 + (lane >> 2);
#pragma unroll
    for (int kk = 0; kk < 2; ++kk) {
      async16(A + (size_t)(m0 + row) * SEQ + kt + kk * 32 + skel, As + kk * 4096 + chunk * 512);
      async16(B + (size_t)(n0 + row) * SEQ + kt + kk * 32 + skel, Bs + kk * 4096 + chunk * 512);
    }
  }
}

__device__ __forceinline__ void compute64(const u16* As, const u16* Bs, f32x4 acc[4][4],
                                          int wr, int wc, int frow, int fk) {
#pragma unroll
  for (int kk = 0; kk < 2; ++kk) {
    const u16* Ap = As + kk * 4096;
    const u16* Bp = Bs + kk * 4096;
    bf16x8 af[4], bfv[4];
#pragma unroll
    for (int mi = 0; mi < 4; ++mi) af[mi] = *(const bf16x8*)&Ap[(wr * 64 + mi * 16 + frow) * 32 + fk];
#pragma unroll
    for (int ni = 0; ni < 4; ++ni) bfv[ni] = *(const bf16x8*)&Bp[(wc * 64 + ni * 16 + frow) * 32 + fk];
#pragma unroll
    for (int mi = 0; mi < 4; ++mi)
#pragma unroll
      for (int ni = 0; ni < 4; ++ni)
        acc[mi][ni] = __builtin_amdgcn_mfma_f32_16x16x32_bf16(af[mi], bfv[ni], acc[mi][ni], 0, 0, 0);
  }
}

// ---------------- fused Q1/K1 GEMM: C[i,j] = sum_k P[i,k]*Wqk[j,k], N=4096, XCD swizzle, BK=64 ----------------
__global__ __launch_bounds__(256) void gemm_qk(const u16* __restrict__ A, const u16* __restrict__ Bw,
                                               u16* __restrict__ Q1b, u16* __restrict__ K1b) {
  __shared__ __align__(16) u16 As0[8192], Bs0[8192], As1[8192], Bs1[8192];
  const int bid = blockIdx.x;  // 512
  const int xcd = bid & 7, li = bid >> 3;
  const int tx = (xcd & 3) * 8 + (li & 7);
  const int ty = (xcd >> 2) * 8 + (li >> 3);
  const int m0 = ty * 128;
  const int n0 = tx * 128;

  const int tid = threadIdx.x;
  const int wid = tid >> 6;
  const int lane = tid & 63;
  const int wr = wid >> 1, wc = wid & 1;
  const int frow = lane & 15;
  const int fk = (lane >> 4) * 8;

  f32x4 acc[4][4];
#pragma unroll
  for (int i = 0; i < 4; ++i)
#pragma unroll
    for (int j = 0; j < 4; ++j) acc[i][j] = (f32x4){0.f, 0.f, 0.f, 0.f};

  stage64(A, Bw, As0, Bs0, m0, n0, 0, wid, lane);
  __syncthreads();
  const int NT = SEQ / 64;  // 32
  for (int t = 0; t < NT - 1; t += 2) {
    stage64(A, Bw, As1, Bs1, m0, n0, (t + 1) * 64, wid, lane);
    compute64(As0, Bs0, acc, wr, wc, frow, fk);
    __syncthreads();
    if (t + 2 < NT) stage64(A, Bw, As0, Bs0, m0, n0, (t + 2) * 64, wid, lane);
    compute64(As1, Bs1, acc, wr, wc, frow, fk);
    __syncthreads();
  }

  u16* outp = (n0 < SEQ) ? Q1b : K1b;
  const int rbase = m0 + wr * 64;
  const int cbase = (n0 < SEQ ? n0 : n0 - SEQ) + wc * 64;
  const int rl = (lane >> 4) * 4;
  const int cl = lane & 15;
#pragma unroll
  for (int mi = 0; mi < 4; ++mi)
#pragma unroll
    for (int ni = 0; ni < 4; ++ni)
#pragma unroll
      for (int i = 0; i < 4; ++i) {
        int rr = rbase + mi * 16 + rl + i;
        int cc = cbase + ni * 16 + cl;
        outp[(size_t)rr * SEQ + cc] = f2bf(acc[mi][ni][i]);
      }
}

// ---------------- S1 partials: tril tiles, split-K4, BK=32, packed bf16 stores (NO atomics) ----------------
__global__ __launch_bounds__(256) void gemm_s1(const u16* __restrict__ A, const u16* __restrict__ B,
                                               u16* __restrict__ part) {
  __shared__ __align__(16) u16 As0[4096], Bs0[4096], As1[4096], Bs1[4096];
  const int bid = blockIdx.x;  // 544 = 136 tril tiles x 4 K-splits
  const int split = bid & 3;
  const int t = bid >> 2;
  int ti_m = 0;
  while (((ti_m + 1) * (ti_m + 2)) / 2 <= t) ++ti_m;
  const int ti_n = t - (ti_m * (ti_m + 1)) / 2;
  const int m0 = ti_m * 128;
  const int n0 = ti_n * 128;
  const int kt0 = split * (SEQ / 4);

  const int tid = threadIdx.x;
  const int wid = tid >> 6;
  const int lane = tid & 63;
  const int wr = wid >> 1, wc = wid & 1;
  const int frow = lane & 15;
  const int fk = (lane >> 4) * 8;

  f32x4 acc[4][4];
#pragma unroll
  for (int i = 0; i < 4; ++i)
#pragma unroll
    for (int j = 0; j < 4; ++j) acc[i][j] = (f32x4){0.f, 0.f, 0.f, 0.f};

  stage_tile(A, B, As0, Bs0, m0, n0, kt0, wid, lane);
  __syncthreads();
  const int NT = (SEQ / 4) / 32;  // 16
  for (int tt = 0; tt < NT - 1; tt += 2) {
    stage_tile(A, B, As1, Bs1, m0, n0, kt0 + (tt + 1) * 32, wid, lane);
    compute_tile(As0, Bs0, acc, wr, wc, frow, fk);
    __syncthreads();
    if (tt + 2 < NT) stage_tile(A, B, As0, Bs0, m0, n0, kt0 + (tt + 2) * 32, wid, lane);
    compute_tile(As1, Bs1, acc, wr, wc, frow, fk);
    __syncthreads();
  }

  u16* dst = part + ((size_t)(split * NTRIL + t) << 14);
  const int rb = wr * 64;
  const int cb = wc * 64;
  const int rl = (lane >> 4) * 4;
  const int cl = lane & 15;
#pragma unroll
  for (int mi = 0; mi < 4; ++mi)
#pragma unroll
    for (int ni = 0; ni < 4; ++ni)
#pragma unroll
      for (int i = 0; i < 4; ++i)
        dst[(rb + mi * 16 + rl + i) * 128 + (cb + ni * 16 + cl)] = f2bf(acc[mi][ni][i]);
}

// ---------------- softmax of row S-1 (sum 4 bf16 partials), MAX-FREE, scatter into cnt1 ----------------
__global__ __launch_bounds__(256) void softmax_last(const u16* __restrict__ part, const float* __restrict__ b1p,
                                                    const int* __restrict__ idx, float* __restrict__ cnt1) {
  const int b = blockIdx.x;  // 8
  const int tid = threadIdx.x, lane = tid & 63, w = tid >> 6;
  __shared__ float buf[SEQ];
  __shared__ float red[8];
  const float c1 = b1p[0] / sqrtf((float)SEQ);
  const int base_t = 120;  // ti_m = 15
  const u16* p0 = part + ((size_t)(0 * NTRIL + base_t) << 14) + 127 * 128;
  const u16* p1 = part + ((size_t)(1 * NTRIL + base_t) << 14) + 127 * 128;
  const u16* p2 = part + ((size_t)(2 * NTRIL + base_t) << 14) + 127 * 128;
  const u16* p3 = part + ((size_t)(3 * NTRIL + base_t) << 14) + 127 * 128;
  float sm = 0.f;
  for (int q = tid; q < SEQ / 4; q += 256) {
    const size_t o = ((size_t)(q >> 5) << 14) + ((q << 2) & 127);
    ushort4 a0 = *(const ushort4*)(p0 + o);
    ushort4 a1 = *(const ushort4*)(p1 + o);
    ushort4 a2 = *(const ushort4*)(p2 + o);
    ushort4 a3 = *(const ushort4*)(p3 + o);
    float v0 = expf((b2f(a0.x) + b2f(a1.x) + b2f(a2.x) + b2f(a3.x)) * c1);
    float v1 = expf((b2f(a0.y) + b2f(a1.y) + b2f(a2.y) + b2f(a3.y)) * c1);
    float v2 = expf((b2f(a0.z) + b2f(a1.z) + b2f(a2.z) + b2f(a3.z)) * c1);
    float v3 = expf((b2f(a0.w) + b2f(a1.w) + b2f(a2.w) + b2f(a3.w)) * c1);
    const int j = q << 2;
    buf[j] = v0; buf[j + 1] = v1; buf[j + 2] = v2; buf[j + 3] = v3;
    sm += v0 + v1 + v2 + v3;
  }
  for (int o = 32; o > 0; o >>= 1) sm += __shfl_down(sm, o);
  if (lane == 0) red[w] = sm;
  __syncthreads();
  if (tid == 0) { float tt = 0.f; for (int i = 0; i < 4; ++i) tt += red[i]; red[5] = tt; }
  __syncthreads();
  const float inv = 1.0f / red[5];
  for (int j = tid; j < SEQ; j += 256)
    atomicAdd(&cnt1[b * VOCAB + idx[b * SEQ + j]], buf[j] * inv);
}

// ---------------- out[b,v] += sc * sum_w x[b,w]*M[w,v], grid (8,64) ----------------
__global__ __launch_bounds__(256) void matvec_col(const float* __restrict__ M, const float* __restrict__ x,
                                                  float* __restrict__ outp, const float* __restrict__ scale_ptr) {
  const int vb = blockIdx.x * 256 + threadIdx.x;
  const int w0 = blockIdx.y * 32;
  __shared__ float xs[BATCH][32];
  { int k = threadIdx.x; xs[k >> 5][k & 31] = x[(k >> 5) * VOCAB + w0 + (k & 31)]; }
  __syncthreads();
  float acc[BATCH];
#pragma unroll
  for (int b = 0; b < BATCH; ++b) acc[b] = 0.f;
#pragma unroll 8
  for (int j = 0; j < 32; ++j) {
    float m = M[(size_t)(w0 + j) * VOCAB + vb];
#pragma unroll
    for (int b = 0; b < BATCH; ++b) acc[b] += xs[b][j] * m;
  }
  float sc = scale_ptr ? scale_ptr[0] : 1.0f;
#pragma unroll
  for (int b = 0; b < BATCH; ++b) atomicAdd(&outp[b * VOCAB + vb], sc * acc[b]);
}

// ---------------- out[b,i] = sum_v M[i,v]*x[b,v], wave-per-row (+ optional emb gather add) ----------------
template<int GATHER_ADD>
__global__ __launch_bounds__(256) void matvec_row(const float* __restrict__ M, const float* __restrict__ x,
                                                  float* __restrict__ outp, const int* __restrict__ idx,
                                                  const float* __restrict__ emb) {
  const int lane = threadIdx.x & 63;
  const int i = blockIdx.x * 4 + (threadIdx.x >> 6);  // grid 512
  const float4* m4 = (const float4*)(M + (size_t)i * VOCAB);
  const float4* x4 = (const float4*)x;
  float acc[BATCH];
#pragma unroll
  for (int b = 0; b < BATCH; ++b) acc[b] = 0.f;
  for (int v = lane; v < VOCAB / 4; v += 64) {
    float4 m = m4[v];
#pragma unroll
    for (int b = 0; b < BATCH; ++b) {
      float4 xv = x4[b * (VOCAB / 4) + v];
      acc[b] += m.x * xv.x + m.y * xv.y + m.z * xv.z + m.w * xv.w;
    }
  }
#pragma unroll
  for (int b = 0; b < BATCH; ++b)
    for (int o = 32; o > 0; o >>= 1) acc[b] += __shfl_down(acc[b], o);
  if (lane == 0) {
#pragma unroll
    for (int b = 0; b < BATCH; ++b) {
      float s = acc[b];
      if (GATHER_ADD) s += emb[(size_t)idx[b * SEQ + SEQ - 1] * VOCAB + i];
      outp[b * VOCAB + i] = s;
    }
  }
}

// ---------------- D[w, j] = sum_v emb[w,v] * rw[j,v]; 2 words per wave, grid 256 ----------------
// Halves the rw L2 re-read (268 MB -> 134 MB) vs 1 word/wave; 1 block/CU, 4 waves/CU.
__global__ __launch_bounds__(256) void emb_dots16(const float* __restrict__ emb, const float* __restrict__ rw,
                                                  float* __restrict__ D) {
  const int lane = threadIdx.x & 63;
  const int i0 = (blockIdx.x * 4 + (threadIdx.x >> 6)) * 2;  // first of 2 vocab words; grid 256
  const float4* e4 = (const float4*)(emb + (size_t)i0 * VOCAB);
  const float4* r4 = (const float4*)rw;
  float acc[2][16];
#pragma unroll
  for (int wi = 0; wi < 2; ++wi)
#pragma unroll
    for (int j = 0; j < 16; ++j) acc[wi][j] = 0.f;
  for (int v = lane; v < VOCAB / 4; v += 64) {
    float4 m0 = e4[v];
    float4 m1 = e4[(VOCAB / 4) + v];
#pragma unroll
    for (int j = 0; j < 16; ++j) {
      float4 r = r4[j * (VOCAB / 4) + v];
      acc[0][j] += m0.x * r.x + m0.y * r.y + m0.z * r.z + m0.w * r.w;
      acc[1][j] += m1.x * r.x + m1.y * r.y + m1.z * r.z + m1.w * r.w;
    }
  }
#pragma unroll
  for (int wi = 0; wi < 2; ++wi)
#pragma unroll
    for (int j = 0; j < 16; ++j)
      for (int o = 32; o > 0; o >>= 1) acc[wi][j] += __shfl_down(acc[wi][j], o);
  if (lane == 0) {
#pragma unroll
    for (int wi = 0; wi < 2; ++wi)
#pragma unroll
      for (int j = 0; j < 16; ++j) D[(size_t)(i0 + wi) * 16 + j] = acc[wi][j];
  }
}

// ---------------- uu[b,s] = D[idx[b,s], 8+b] ----------------
__global__ __launch_bounds__(256) void gath_u(const int* __restrict__ idx, const float* __restrict__ D,
                                              float* __restrict__ u) {
  const int i = blockIdx.x * 256 + threadIdx.x;  // 16384
  const int b = i >> 11;
  u[i] = D[(size_t)idx[i] * 16 + 8 + b];
}

// ---------------- fused causal softmax(row s, sum 4 bf16 partials) . u -> vv[b,s], MAX-FREE ----------------
// longest rows launched first for better makespan packing (R7 measured-best form)
__global__ __launch_bounds__(256) void sm_apply(const u16* __restrict__ part, const float* __restrict__ b1p,
                                                const float* __restrict__ u, float* __restrict__ vv) {
  const int s = SEQ - 1 - blockIdx.x;
  const int tid = threadIdx.x, lane = tid & 63, w = tid >> 6;
  if (s == 0) {
    if (tid < BATCH) vv[tid * SEQ] = 0.f;  // A1 row 0 is zeroed
    return;
  }
  __shared__ float buf[SEQ];
  __shared__ float red[8];
  __shared__ float red2[4][BATCH];
  const float c1 = b1p[0] / sqrtf((float)SEQ);
  const int base_t = (s >> 7) * ((s >> 7) + 1) / 2;
  const int rloc = (s & 127) * 128;
  const u16* p0 = part + ((size_t)(0 * NTRIL + base_t) << 14) + rloc;
  const u16* p1 = part + ((size_t)(1 * NTRIL + base_t) << 14) + rloc;
  const u16* p2 = part + ((size_t)(2 * NTRIL + base_t) << 14) + rloc;
  const u16* p3 = part + ((size_t)(3 * NTRIL + base_t) << 14) + rloc;
  float sm = 0.f;
  const int nq = (s + 1) >> 2;  // full quads
  for (int q = tid; q < nq; q += 256) {
    const size_t o = ((size_t)(q >> 5) << 14) + ((q << 2) & 127);
    ushort4 a0 = *(const ushort4*)(p0 + o);
    ushort4 a1 = *(const ushort4*)(p1 + o);
    ushort4 a2 = *(const ushort4*)(p2 + o);
    ushort4 a3 = *(const ushort4*)(p3 + o);
    float v0 = expf((b2f(a0.x) + b2f(a1.x) + b2f(a2.x) + b2f(a3.x)) * c1);
    float v1 = expf((b2f(a0.y) + b2f(a1.y) + b2f(a2.y) + b2f(a3.y)) * c1);
    float v2 = expf((b2f(a0.z) + b2f(a1.z) + b2f(a2.z) + b2f(a3.z)) * c1);
    float v3 = expf((b2f(a0.w) + b2f(a1.w) + b2f(a2.w) + b2f(a3.w)) * c1);
    const int j = q << 2;
    buf[j] = v0; buf[j + 1] = v1; buf[j + 2] = v2; buf[j + 3] = v3;
    sm += v0 + v1 + v2 + v3;
  }
  {
    const int j = (nq << 2) + tid;
    if (j <= s) {
      const size_t o = ((size_t)(j >> 7) << 14) + (j & 127);
      float v = expf((b2f(p0[o]) + b2f(p1[o]) + b2f(p2[o]) + b2f(p3[o])) * c1);
      buf[j] = v;
      sm += v;
    }
  }
  for (int o = 32; o > 0; o >>= 1) sm += __shfl_down(sm, o);
  if (lane == 0) red[w] = sm;
  __syncthreads();
  if (tid == 0) { float tt = 0.f; for (int i = 0; i < 4; ++i) tt += red[i]; red[5] = tt; }
  __syncthreads();
  const float inv = 1.0f / red[5];
  float acc[BATCH];
#pragma unroll
  for (int b = 0; b < BATCH; ++b) acc[b] = 0.f;
  for (int q = tid; q < nq; q += 256) {
    const int j = q << 2;
    float4 a = *(float4*)&buf[j];
#pragma unroll
    for (int b = 0; b < BATCH; ++b) {
      float4 uv = *(const float4*)(u + b * SEQ + j);
      acc[b] += a.x * uv.x + a.y * uv.y + a.z * uv.z + a.w * uv.w;
    }
  }
  {
    const int j = (nq << 2) + tid;
    if (j <= s) {
      float a = buf[j];
#pragma unroll
      for (int b = 0; b < BATCH; ++b) acc[b] += a * u[b * SEQ + j];
    }
  }
#pragma unroll
  for (int b = 0; b < BATCH; ++b)
    for (int o = 32; o > 0; o >>= 1) acc[b] += __shfl_down(acc[b], o);
  if (lane == 0)
#pragma unroll
    for (int b = 0; b < BATCH; ++b) red2[w][b] = acc[b];
  __syncthreads();
  if (tid < BATCH)
    vv[tid * SEQ + s] = (red2[0][tid] + red2[1][tid] + red2[2][tid] + red2[3][tid]) * inv;
}

// ---------------- A2 softmax (MAX-FREE) + scatter into cnt2[b,w]; also zeroes `out` ----------------
__global__ __launch_bounds__(256) void softmax2(const float* __restrict__ D, const float* __restrict__ vv,
                                                const int* __restrict__ idx, float* __restrict__ cnt2,
                                                const float* __restrict__ b2p, float4* __restrict__ out_zero) {
  const int b = blockIdx.x;
  const int tid = threadIdx.x, lane = tid & 63, w = tid >> 6;
  for (int k = b * 256 + tid; k < BATCH * VOCAB / 4; k += BATCH * 256)
    out_zero[k] = make_float4(0.f, 0.f, 0.f, 0.f);
  __shared__ float buf[SEQ];
  __shared__ float red[8];
  const float c2 = b2p[0] / sqrtf((float)VOCAB);
  float sm = 0.f;
  for (int s = tid; s < SEQ; s += 256) {
    float e = 0.f;
    if (s < SEQ - 2) {
      float ee = D[(size_t)idx[b * SEQ + s] * 16 + b];
      e = expf(c2 * (ee + vv[b * SEQ + s]));
    }
    buf[s] = e;
    sm += e;
  }
  for (int o = 32; o > 0; o >>= 1) sm += __shfl_down(sm, o);
  if (lane == 0) red[w] = sm;
  __syncthreads();
  if (tid == 0) { float tt = 0.f; for (int i = 0; i < 4; ++i) tt += red[i]; red[5] = tt; }
  __syncthreads();
  const float inv = 1.0f / red[5];
  for (int s = tid; s < SEQ - 2; s += 256)
    atomicAdd(&cnt2[b * VOCAB + idx[b * SEQ + s]], buf[s] * inv);
}

extern "C" void kernel_launch(void* const* d_in, const int* in_sizes, int n_in,
                              void* d_out, int out_size, void* d_ws, size_t ws_size,
                              hipStream_t stream) {
  (void)in_sizes; (void)n_in; (void)out_size; (void)ws_size;
  const int*   idx = (const int*)d_in[0];
  const float* emb = (const float*)d_in[1];
  const float* pos = (const float*)d_in[2];
  const float* WQ1 = (const float*)d_in[3];
  const float* WK1 = (const float*)d_in[4];
  const float* WV1 = (const float*)d_in[5];
  const float* WQ2 = (const float*)d_in[6];
  const float* WK2 = (const float*)d_in[7];
  const float* b1  = (const float*)d_in[8];
  const float* b2  = (const float*)d_in[9];
  const float* bo  = (const float*)d_in[10];
  float* out = (float*)d_out;

  size_t off = 0;
  auto take = [&](size_t n) { void* p = (char*)d_ws + off; off += (n + 255) & ~(size_t)255; return p; };
  u16*   Pbf  = (u16*)take((size_t)SEQ * SEQ * 2);
  u16*   Wqk  = (u16*)take((size_t)SEQ * SEQ * 4);  // [WQ1bf ; WK1bf], 4096 x 2048
  u16*   Q1b  = (u16*)take((size_t)SEQ * SEQ * 2);
  u16*   K1b  = (u16*)take((size_t)SEQ * SEQ * 2);
  u16*   S1p  = (u16*)take((size_t)4 * NTRIL * 16384 * 2);  // packed bf16 split-K partials, ~17.8 MB
  // ---- zero-init region (zeroed in cvt_all seg 3): g, cnt1, rr, wv, cnt2 ----
  float* g    = (float*)take((size_t)BATCH * VOCAB * 4);
  float* cnt1 = (float*)take((size_t)BATCH * VOCAB * 4);
  float* rr   = (float*)take((size_t)BATCH * VOCAB * 4);  // rr & wv contiguous -> rw[16][V]
  float* wv   = (float*)take((size_t)BATCH * VOCAB * 4);
  float* cnt2 = (float*)take((size_t)BATCH * VOCAB * 4);
  // ---- plain scratch (fully overwritten) ----
  float* zl   = (float*)take((size_t)BATCH * VOCAB * 4);
  float* q2   = (float*)take((size_t)BATCH * VOCAB * 4);
  float* D    = (float*)take((size_t)VOCAB * 16 * 4);
  float* uu   = (float*)take((size_t)BATCH * SEQ * 4);
  float* vv   = (float*)take((size_t)BATCH * SEQ * 4);
  (void)wv;

  const int nz4 = 5 * BATCH * VOCAB / 4;  // 20480 float4s to zero (g..cnt2)

  // convert P, WQ1, WK1 to bf16 + zero the atomic-target region
  cvt_all<<<dim3(SEQ * SEQ / 4 / 256, 4), 256, 0, stream>>>(pos, WQ1, WK1, Pbf, Wqk, (float4*)g, nz4);

  // fused Q1|K1 GEMM: 512 blocks, BK=64 2-phase dbuf, XCD-chunked swizzle
  gemm_qk<<<512, 256, 0, stream>>>(Pbf, Wqk, Q1b, K1b);

  // S1 partials: tril tiles, split-K4, BK=32, bf16 packed stores
  gemm_s1<<<4 * NTRIL, 256, 0, stream>>>(Q1b, K1b, S1p);

  // softmax of row S-1 -> scatter cnt1[b,w]
  softmax_last<<<BATCH, 256, 0, stream>>>(S1p, b1, idx, cnt1);

  // g[b] = sum_w cnt1[b,w] emb[w,:]
  matvec_col<<<dim3(VOCAB / 256, 64), 256, 0, stream>>>(emb, cnt1, g, nullptr);

  // z_last[b] = E[b,S-1] + WV1 g[b];  q2[b] = WQ2 z_last[b]
  matvec_row<1><<<VOCAB / 4, 256, 0, stream>>>(WV1, g, zl, idx, emb);
  matvec_row<0><<<VOCAB / 4, 256, 0, stream>>>(WQ2, zl, q2, nullptr, nullptr);

  // rr[b] = WK2^T q2[b];  wv[b] = WV1^T rr[b]
  matvec_col<<<dim3(VOCAB / 256, 64), 256, 0, stream>>>(WK2, q2, rr, nullptr);
  matvec_col<<<dim3(VOCAB / 256, 64), 256, 0, stream>>>(WV1, rr, wv, nullptr);

  // D[w,j] = emb[w] . rw[j]  (j=0..7 -> rr, 8..15 -> wv); 2 words/wave
  emb_dots16<<<VOCAB / 8, 256, 0, stream>>>(emb, rr, D);

  // uu[b,s] = D[idx[b,s], 8+b]
  gath_u<<<BATCH * SEQ / 256, 256, 0, stream>>>(idx, D, uu);

  // vv[b,s] = softmax_causal(row s) . u[b,:]  (longest rows first)
  sm_apply<<<SEQ, 256, 0, stream>>>(S1p, b1, uu, vv);

  // A2 softmax -> scatter cnt2 (also zeroes out)
  softmax2<<<BATCH, 256, 0, stream>>>(D, vv, idx, cnt2, b2, (float4*)out);

  // out[b] = beta_out * sum_w cnt2[b,w] emb[w,:]
  matvec_col<<<dim3(VOCAB / 256, 64), 256, 0, stream>>>(emb, cnt2, out, bo);
}

// Round 13
// 157.178 us; speedup vs baseline: 1.1383x; 1.1383x over previous
//
#include <hip/hip_runtime.h>
#include <math.h>

#define SEQ 2048
#define VOCAB 2048
#define BATCH 8
#define NTRIL 136  // 16*17/2 lower-tri 128x128 tiles

typedef unsigned short u16;
typedef __attribute__((ext_vector_type(4))) float f32x4;
typedef __attribute__((ext_vector_type(8))) short bf16x8;

__device__ __forceinline__ u16 f2bf(float f) {
  unsigned int u = __builtin_bit_cast(unsigned int, f);
  u += 0x7fffu + ((u >> 16) & 1u);
  return (u16)(u >> 16);
}

__device__ __forceinline__ float b2f(u16 h) {
  unsigned int u = ((unsigned int)h) << 16;
  return __builtin_bit_cast(float, u);
}

__device__ __forceinline__ void async16(const void* g, void* l) {
  __builtin_amdgcn_global_load_lds((const __attribute__((address_space(1))) void*)g,
                                   (__attribute__((address_space(3))) void*)l, 16, 0, 0);
}

// ---------------- f32 -> bf16 convert (3 arrays) + zero-region, one launch ----------------
__global__ __launch_bounds__(256) void cvt_all(const float* __restrict__ pos, const float* __restrict__ WQ1,
                                               const float* __restrict__ WK1, u16* __restrict__ Pbf,
                                               u16* __restrict__ Wqk, float4* __restrict__ zreg, int nz4) {
  const int i = blockIdx.x * 256 + threadIdx.x;  // over SEQ*SEQ/4 float4s
  const int seg = blockIdx.y;
  if (seg == 3) {
    if (i < nz4) zreg[i] = make_float4(0.f, 0.f, 0.f, 0.f);
    return;
  }
  const float* src = (seg == 0) ? pos : (seg == 1) ? WQ1 : WK1;
  u16* dst = (seg == 0) ? Pbf : (seg == 1) ? Wqk : Wqk + (size_t)SEQ * SEQ;
  float4 v = ((const float4*)src)[i];
  ushort4 o;
  o.x = f2bf(v.x); o.y = f2bf(v.y); o.z = f2bf(v.z); o.w = f2bf(v.w);
  ((ushort4*)dst)[i] = o;
}

// ---------------- BK=32 helpers (gemm_s1): LDS [128][32] per buffer ----------------
// NOTE: gemm_s1 must stay at BK=32 / 32KB LDS — BK=64 (64KB) regressed ~30µs in R6
// (occupancy cliff: split-K grid needs >2 blocks/CU co-residency to hide stragglers).
// NOTE: cooperative-kernel tail fusion (R8) fails under graph capture — kernel never runs.
// NOTE: 4-rows-per-block balanced sm_apply (R9) regressed vs 2048-block longest-first.
// NOTE: max-free softmax is safe here: logits ~N(0,~1.5), max |logit| < 8 << 88 (f32 exp range).
// NOTE: emb_dots16 must stay 1 word/wave grid 512 — 2 words/wave grid 256 (R12) cost +21µs
// (latency-bound: 4 waves/CU can't hide L2 latency; traffic saving irrelevant).
__device__ __forceinline__ void stage_tile(const u16* __restrict__ A, const u16* __restrict__ B,
                                           u16* As, u16* Bs, int m0, int n0, int kt,
                                           int wid, int lane) {
  const int c0 = wid * 2;
  const int skel = (lane & 3) * 8;
#pragma unroll
  for (int r = 0; r < 2; ++r) {
    const int chunk = c0 + r;
    const int row = chunk * 16 + (lane >> 2);
    async16(A + (size_t)(m0 + row) * SEQ + kt + skel, As + chunk * 512);
    async16(B + (size_t)(n0 + row) * SEQ + kt + skel, Bs + chunk * 512);
  }
}

__device__ __forceinline__ void compute_tile(const u16* As, const u16* Bs, f32x4 acc[4][4],
                                             int wr, int wc, int frow, int fk) {
  bf16x8 af[4], bfv[4];
#pragma unroll
  for (int mi = 0; mi < 4; ++mi) af[mi] = *(const bf16x8*)&As[(wr * 64 + mi * 16 + frow) * 32 + fk];
#pragma unroll
  for (int ni = 0; ni < 4; ++ni) bfv[ni] = *(const bf16x8*)&Bs[(wc * 64 + ni * 16 + frow) * 32 + fk];
#pragma unroll
  for (int mi = 0; mi < 4; ++mi)
#pragma unroll
    for (int ni = 0; ni < 4; ++ni)
      acc[mi][ni] = __builtin_amdgcn_mfma_f32_16x16x32_bf16(af[mi], bfv[ni], acc[mi][ni], 0, 0, 0);
}

// ---------------- BK=64 helpers (gemm_qk): LDS [2][128][32] per buffer ----------------
__device__ __forceinline__ void stage64(const u16* __restrict__ A, const u16* __restrict__ B,
                                        u16* As, u16* Bs, int m0, int n0, int kt,
                                        int wid, int lane) {
  const int c0 = wid * 2;
  const int skel = (lane & 3) * 8;
#pragma unroll
  for (int r = 0; r < 2; ++r) {
    const int chunk = c0 + r;
    const int row = chunk * 16 + (lane >> 2);
#pragma unroll
    for (int kk = 0; kk < 2; ++kk) {
      async16(A + (size_t)(m0 + row) * SEQ + kt + kk * 32 + skel, As + kk * 4096 + chunk * 512);
      async16(B + (size_t)(n0 + row) * SEQ + kt + kk * 32 + skel, Bs + kk * 4096 + chunk * 512);
    }
  }
}

__device__ __forceinline__ void compute64(const u16* As, const u16* Bs, f32x4 acc[4][4],
                                          int wr, int wc, int frow, int fk) {
#pragma unroll
  for (int kk = 0; kk < 2; ++kk) {
    const u16* Ap = As + kk * 4096;
    const u16* Bp = Bs + kk * 4096;
    bf16x8 af[4], bfv[4];
#pragma unroll
    for (int mi = 0; mi < 4; ++mi) af[mi] = *(const bf16x8*)&Ap[(wr * 64 + mi * 16 + frow) * 32 + fk];
#pragma unroll
    for (int ni = 0; ni < 4; ++ni) bfv[ni] = *(const bf16x8*)&Bp[(wc * 64 + ni * 16 + frow) * 32 + fk];
#pragma unroll
    for (int mi = 0; mi < 4; ++mi)
#pragma unroll
      for (int ni = 0; ni < 4; ++ni)
        acc[mi][ni] = __builtin_amdgcn_mfma_f32_16x16x32_bf16(af[mi], bfv[ni], acc[mi][ni], 0, 0, 0);
  }
}

// ---------------- fused Q1/K1 GEMM: C[i,j] = sum_k P[i,k]*Wqk[j,k], N=4096, XCD swizzle, BK=64 ----------------
__global__ __launch_bounds__(256) void gemm_qk(const u16* __restrict__ A, const u16* __restrict__ Bw,
                                               u16* __restrict__ Q1b, u16* __restrict__ K1b) {
  __shared__ __align__(16) u16 As0[8192], Bs0[8192], As1[8192], Bs1[8192];
  const int bid = blockIdx.x;  // 512
  const int xcd = bid & 7, li = bid >> 3;
  const int tx = (xcd & 3) * 8 + (li & 7);
  const int ty = (xcd >> 2) * 8 + (li >> 3);
  const int m0 = ty * 128;
  const int n0 = tx * 128;

  const int tid = threadIdx.x;
  const int wid = tid >> 6;
  const int lane = tid & 63;
  const int wr = wid >> 1, wc = wid & 1;
  const int frow = lane & 15;
  const int fk = (lane >> 4) * 8;

  f32x4 acc[4][4];
#pragma unroll
  for (int i = 0; i < 4; ++i)
#pragma unroll
    for (int j = 0; j < 4; ++j) acc[i][j] = (f32x4){0.f, 0.f, 0.f, 0.f};

  stage64(A, Bw, As0, Bs0, m0, n0, 0, wid, lane);
  __syncthreads();
  const int NT = SEQ / 64;  // 32
  for (int t = 0; t < NT - 1; t += 2) {
    stage64(A, Bw, As1, Bs1, m0, n0, (t + 1) * 64, wid, lane);
    compute64(As0, Bs0, acc, wr, wc, frow, fk);
    __syncthreads();
    if (t + 2 < NT) stage64(A, Bw, As0, Bs0, m0, n0, (t + 2) * 64, wid, lane);
    compute64(As1, Bs1, acc, wr, wc, frow, fk);
    __syncthreads();
  }

  u16* outp = (n0 < SEQ) ? Q1b : K1b;
  const int rbase = m0 + wr * 64;
  const int cbase = (n0 < SEQ ? n0 : n0 - SEQ) + wc * 64;
  const int rl = (lane >> 4) * 4;
  const int cl = lane & 15;
#pragma unroll
  for (int mi = 0; mi < 4; ++mi)
#pragma unroll
    for (int ni = 0; ni < 4; ++ni)
#pragma unroll
      for (int i = 0; i < 4; ++i) {
        int rr = rbase + mi * 16 + rl + i;
        int cc = cbase + ni * 16 + cl;
        outp[(size_t)rr * SEQ + cc] = f2bf(acc[mi][ni][i]);
      }
}

// ---------------- S1 partials: tril tiles, split-K4, BK=32, packed bf16 stores (NO atomics) ----------------
__global__ __launch_bounds__(256) void gemm_s1(const u16* __restrict__ A, const u16* __restrict__ B,
                                               u16* __restrict__ part) {
  __shared__ __align__(16) u16 As0[4096], Bs0[4096], As1[4096], Bs1[4096];
  const int bid = blockIdx.x;  // 544 = 136 tril tiles x 4 K-splits
  const int split = bid & 3;
  const int t = bid >> 2;
  int ti_m = 0;
  while (((ti_m + 1) * (ti_m + 2)) / 2 <= t) ++ti_m;
  const int ti_n = t - (ti_m * (ti_m + 1)) / 2;
  const int m0 = ti_m * 128;
  const int n0 = ti_n * 128;
  const int kt0 = split * (SEQ / 4);

  const int tid = threadIdx.x;
  const int wid = tid >> 6;
  const int lane = tid & 63;
  const int wr = wid >> 1, wc = wid & 1;
  const int frow = lane & 15;
  const int fk = (lane >> 4) * 8;

  f32x4 acc[4][4];
#pragma unroll
  for (int i = 0; i < 4; ++i)
#pragma unroll
    for (int j = 0; j < 4; ++j) acc[i][j] = (f32x4){0.f, 0.f, 0.f, 0.f};

  stage_tile(A, B, As0, Bs0, m0, n0, kt0, wid, lane);
  __syncthreads();
  const int NT = (SEQ / 4) / 32;  // 16
  for (int tt = 0; tt < NT - 1; tt += 2) {
    stage_tile(A, B, As1, Bs1, m0, n0, kt0 + (tt + 1) * 32, wid, lane);
    compute_tile(As0, Bs0, acc, wr, wc, frow, fk);
    __syncthreads();
    if (tt + 2 < NT) stage_tile(A, B, As0, Bs0, m0, n0, kt0 + (tt + 2) * 32, wid, lane);
    compute_tile(As1, Bs1, acc, wr, wc, frow, fk);
    __syncthreads();
  }

  u16* dst = part + ((size_t)(split * NTRIL + t) << 14);
  const int rb = wr * 64;
  const int cb = wc * 64;
  const int rl = (lane >> 4) * 4;
  const int cl = lane & 15;
#pragma unroll
  for (int mi = 0; mi < 4; ++mi)
#pragma unroll
    for (int ni = 0; ni < 4; ++ni)
#pragma unroll
      for (int i = 0; i < 4; ++i)
        dst[(rb + mi * 16 + rl + i) * 128 + (cb + ni * 16 + cl)] = f2bf(acc[mi][ni][i]);
}

// ---------------- softmax of row S-1 (sum 4 bf16 partials), MAX-FREE, scatter into cnt1 ----------------
__global__ __launch_bounds__(256) void softmax_last(const u16* __restrict__ part, const float* __restrict__ b1p,
                                                    const int* __restrict__ idx, float* __restrict__ cnt1) {
  const int b = blockIdx.x;  // 8
  const int tid = threadIdx.x, lane = tid & 63, w = tid >> 6;
  __shared__ float buf[SEQ];
  __shared__ float red[8];
  const float c1 = b1p[0] / sqrtf((float)SEQ);
  const int base_t = 120;  // ti_m = 15
  const u16* p0 = part + ((size_t)(0 * NTRIL + base_t) << 14) + 127 * 128;
  const u16* p1 = part + ((size_t)(1 * NTRIL + base_t) << 14) + 127 * 128;
  const u16* p2 = part + ((size_t)(2 * NTRIL + base_t) << 14) + 127 * 128;
  const u16* p3 = part + ((size_t)(3 * NTRIL + base_t) << 14) + 127 * 128;
  float sm = 0.f;
  for (int q = tid; q < SEQ / 4; q += 256) {
    const size_t o = ((size_t)(q >> 5) << 14) + ((q << 2) & 127);
    ushort4 a0 = *(const ushort4*)(p0 + o);
    ushort4 a1 = *(const ushort4*)(p1 + o);
    ushort4 a2 = *(const ushort4*)(p2 + o);
    ushort4 a3 = *(const ushort4*)(p3 + o);
    float v0 = expf((b2f(a0.x) + b2f(a1.x) + b2f(a2.x) + b2f(a3.x)) * c1);
    float v1 = expf((b2f(a0.y) + b2f(a1.y) + b2f(a2.y) + b2f(a3.y)) * c1);
    float v2 = expf((b2f(a0.z) + b2f(a1.z) + b2f(a2.z) + b2f(a3.z)) * c1);
    float v3 = expf((b2f(a0.w) + b2f(a1.w) + b2f(a2.w) + b2f(a3.w)) * c1);
    const int j = q << 2;
    buf[j] = v0; buf[j + 1] = v1; buf[j + 2] = v2; buf[j + 3] = v3;
    sm += v0 + v1 + v2 + v3;
  }
  for (int o = 32; o > 0; o >>= 1) sm += __shfl_down(sm, o);
  if (lane == 0) red[w] = sm;
  __syncthreads();
  if (tid == 0) { float tt = 0.f; for (int i = 0; i < 4; ++i) tt += red[i]; red[5] = tt; }
  __syncthreads();
  const float inv = 1.0f / red[5];
  for (int j = tid; j < SEQ; j += 256)
    atomicAdd(&cnt1[b * VOCAB + idx[b * SEQ + j]], buf[j] * inv);
}

// ---------------- out[b,v] += sc * sum_w x[b,w]*M[w,v], grid (8,64) ----------------
__global__ __launch_bounds__(256) void matvec_col(const float* __restrict__ M, const float* __restrict__ x,
                                                  float* __restrict__ outp, const float* __restrict__ scale_ptr) {
  const int vb = blockIdx.x * 256 + threadIdx.x;
  const int w0 = blockIdx.y * 32;
  __shared__ float xs[BATCH][32];
  { int k = threadIdx.x; xs[k >> 5][k & 31] = x[(k >> 5) * VOCAB + w0 + (k & 31)]; }
  __syncthreads();
  float acc[BATCH];
#pragma unroll
  for (int b = 0; b < BATCH; ++b) acc[b] = 0.f;
#pragma unroll 8
  for (int j = 0; j < 32; ++j) {
    float m = M[(size_t)(w0 + j) * VOCAB + vb];
#pragma unroll
    for (int b = 0; b < BATCH; ++b) acc[b] += xs[b][j] * m;
  }
  float sc = scale_ptr ? scale_ptr[0] : 1.0f;
#pragma unroll
  for (int b = 0; b < BATCH; ++b) atomicAdd(&outp[b * VOCAB + vb], sc * acc[b]);
}

// ---------------- out[b,i] = sum_v M[i,v]*x[b,v], wave-per-row (+ optional emb gather add) ----------------
template<int GATHER_ADD>
__global__ __launch_bounds__(256) void matvec_row(const float* __restrict__ M, const float* __restrict__ x,
                                                  float* __restrict__ outp, const int* __restrict__ idx,
                                                  const float* __restrict__ emb) {
  const int lane = threadIdx.x & 63;
  const int i = blockIdx.x * 4 + (threadIdx.x >> 6);  // grid 512
  const float4* m4 = (const float4*)(M + (size_t)i * VOCAB);
  const float4* x4 = (const float4*)x;
  float acc[BATCH];
#pragma unroll
  for (int b = 0; b < BATCH; ++b) acc[b] = 0.f;
  for (int v = lane; v < VOCAB / 4; v += 64) {
    float4 m = m4[v];
#pragma unroll
    for (int b = 0; b < BATCH; ++b) {
      float4 xv = x4[b * (VOCAB / 4) + v];
      acc[b] += m.x * xv.x + m.y * xv.y + m.z * xv.z + m.w * xv.w;
    }
  }
#pragma unroll
  for (int b = 0; b < BATCH; ++b)
    for (int o = 32; o > 0; o >>= 1) acc[b] += __shfl_down(acc[b], o);
  if (lane == 0) {
#pragma unroll
    for (int b = 0; b < BATCH; ++b) {
      float s = acc[b];
      if (GATHER_ADD) s += emb[(size_t)idx[b * SEQ + SEQ - 1] * VOCAB + i];
      outp[b * VOCAB + i] = s;
    }
  }
}

// ---------------- D[w, j] = sum_v emb[w,v] * rw[j,v], wave-per-word, j=0..15 ----------------
__global__ __launch_bounds__(256) void emb_dots16(const float* __restrict__ emb, const float* __restrict__ rw,
                                                  float* __restrict__ D) {
  const int lane = threadIdx.x & 63;
  const int i = blockIdx.x * 4 + (threadIdx.x >> 6);  // grid 512
  const float4* e4 = (const float4*)(emb + (size_t)i * VOCAB);
  const float4* r4 = (const float4*)rw;
  float acc[16];
#pragma unroll
  for (int j = 0; j < 16; ++j) acc[j] = 0.f;
  for (int v = lane; v < VOCAB / 4; v += 64) {
    float4 m = e4[v];
#pragma unroll
    for (int j = 0; j < 16; ++j) {
      float4 r = r4[j * (VOCAB / 4) + v];
      acc[j] += m.x * r.x + m.y * r.y + m.z * r.z + m.w * r.w;
    }
  }
#pragma unroll
  for (int j = 0; j < 16; ++j)
    for (int o = 32; o > 0; o >>= 1) acc[j] += __shfl_down(acc[j], o);
  if (lane == 0) {
#pragma unroll
    for (int j = 0; j < 16; ++j) D[(size_t)i * 16 + j] = acc[j];
  }
}

// ---------------- uu[b,s] = D[idx[b,s], 8+b] ----------------
__global__ __launch_bounds__(256) void gath_u(const int* __restrict__ idx, const float* __restrict__ D,
                                              float* __restrict__ u) {
  const int i = blockIdx.x * 256 + threadIdx.x;  // 16384
  const int b = i >> 11;
  u[i] = D[(size_t)idx[i] * 16 + 8 + b];
}

// ---------------- fused causal softmax(row s, sum 4 bf16 partials) . u -> vv[b,s], MAX-FREE ----------------
// longest rows launched first for better makespan packing (R7 measured-best form)
__global__ __launch_bounds__(256) void sm_apply(const u16* __restrict__ part, const float* __restrict__ b1p,
                                                const float* __restrict__ u, float* __restrict__ vv) {
  const int s = SEQ - 1 - blockIdx.x;
  const int tid = threadIdx.x, lane = tid & 63, w = tid >> 6;
  if (s == 0) {
    if (tid < BATCH) vv[tid * SEQ] = 0.f;  // A1 row 0 is zeroed
    return;
  }
  __shared__ float buf[SEQ];
  __shared__ float red[8];
  __shared__ float red2[4][BATCH];
  const float c1 = b1p[0] / sqrtf((float)SEQ);
  const int base_t = (s >> 7) * ((s >> 7) + 1) / 2;
  const int rloc = (s & 127) * 128;
  const u16* p0 = part + ((size_t)(0 * NTRIL + base_t) << 14) + rloc;
  const u16* p1 = part + ((size_t)(1 * NTRIL + base_t) << 14) + rloc;
  const u16* p2 = part + ((size_t)(2 * NTRIL + base_t) << 14) + rloc;
  const u16* p3 = part + ((size_t)(3 * NTRIL + base_t) << 14) + rloc;
  float sm = 0.f;
  const int nq = (s + 1) >> 2;  // full quads
  for (int q = tid; q < nq; q += 256) {
    const size_t o = ((size_t)(q >> 5) << 14) + ((q << 2) & 127);
    ushort4 a0 = *(const ushort4*)(p0 + o);
    ushort4 a1 = *(const ushort4*)(p1 + o);
    ushort4 a2 = *(const ushort4*)(p2 + o);
    ushort4 a3 = *(const ushort4*)(p3 + o);
    float v0 = expf((b2f(a0.x) + b2f(a1.x) + b2f(a2.x) + b2f(a3.x)) * c1);
    float v1 = expf((b2f(a0.y) + b2f(a1.y) + b2f(a2.y) + b2f(a3.y)) * c1);
    float v2 = expf((b2f(a0.z) + b2f(a1.z) + b2f(a2.z) + b2f(a3.z)) * c1);
    float v3 = expf((b2f(a0.w) + b2f(a1.w) + b2f(a2.w) + b2f(a3.w)) * c1);
    const int j = q << 2;
    buf[j] = v0; buf[j + 1] = v1; buf[j + 2] = v2; buf[j + 3] = v3;
    sm += v0 + v1 + v2 + v3;
  }
  {
    const int j = (nq << 2) + tid;
    if (j <= s) {
      const size_t o = ((size_t)(j >> 7) << 14) + (j & 127);
      float v = expf((b2f(p0[o]) + b2f(p1[o]) + b2f(p2[o]) + b2f(p3[o])) * c1);
      buf[j] = v;
      sm += v;
    }
  }
  for (int o = 32; o > 0; o >>= 1) sm += __shfl_down(sm, o);
  if (lane == 0) red[w] = sm;
  __syncthreads();
  if (tid == 0) { float tt = 0.f; for (int i = 0; i < 4; ++i) tt += red[i]; red[5] = tt; }
  __syncthreads();
  const float inv = 1.0f / red[5];
  float acc[BATCH];
#pragma unroll
  for (int b = 0; b < BATCH; ++b) acc[b] = 0.f;
  for (int q = tid; q < nq; q += 256) {
    const int j = q << 2;
    float4 a = *(float4*)&buf[j];
#pragma unroll
    for (int b = 0; b < BATCH; ++b) {
      float4 uv = *(const float4*)(u + b * SEQ + j);
      acc[b] += a.x * uv.x + a.y * uv.y + a.z * uv.z + a.w * uv.w;
    }
  }
  {
    const int j = (nq << 2) + tid;
    if (j <= s) {
      float a = buf[j];
#pragma unroll
      for (int b = 0; b < BATCH; ++b) acc[b] += a * u[b * SEQ + j];
    }
  }
#pragma unroll
  for (int b = 0; b < BATCH; ++b)
    for (int o = 32; o > 0; o >>= 1) acc[b] += __shfl_down(acc[b], o);
  if (lane == 0)
#pragma unroll
    for (int b = 0; b < BATCH; ++b) red2[w][b] = acc[b];
  __syncthreads();
  if (tid < BATCH)
    vv[tid * SEQ + s] = (red2[0][tid] + red2[1][tid] + red2[2][tid] + red2[3][tid]) * inv;
}

// ---------------- A2 softmax (MAX-FREE) + scatter into cnt2[b,w]; also zeroes `out` ----------------
__global__ __launch_bounds__(256) void softmax2(const float* __restrict__ D, const float* __restrict__ vv,
                                                const int* __restrict__ idx, float* __restrict__ cnt2,
                                                const float* __restrict__ b2p, float4* __restrict__ out_zero) {
  const int b = blockIdx.x;
  const int tid = threadIdx.x, lane = tid & 63, w = tid >> 6;
  for (int k = b * 256 + tid; k < BATCH * VOCAB / 4; k += BATCH * 256)
    out_zero[k] = make_float4(0.f, 0.f, 0.f, 0.f);
  __shared__ float buf[SEQ];
  __shared__ float red[8];
  const float c2 = b2p[0] / sqrtf((float)VOCAB);
  float sm = 0.f;
  for (int s = tid; s < SEQ; s += 256) {
    float e = 0.f;
    if (s < SEQ - 2) {
      float ee = D[(size_t)idx[b * SEQ + s] * 16 + b];
      e = expf(c2 * (ee + vv[b * SEQ + s]));
    }
    buf[s] = e;
    sm += e;
  }
  for (int o = 32; o > 0; o >>= 1) sm += __shfl_down(sm, o);
  if (lane == 0) red[w] = sm;
  __syncthreads();
  if (tid == 0) { float tt = 0.f; for (int i = 0; i < 4; ++i) tt += red[i]; red[5] = tt; }
  __syncthreads();
  const float inv = 1.0f / red[5];
  for (int s = tid; s < SEQ - 2; s += 256)
    atomicAdd(&cnt2[b * VOCAB + idx[b * SEQ + s]], buf[s] * inv);
}

extern "C" void kernel_launch(void* const* d_in, const int* in_sizes, int n_in,
                              void* d_out, int out_size, void* d_ws, size_t ws_size,
                              hipStream_t stream) {
  (void)in_sizes; (void)n_in; (void)out_size; (void)ws_size;
  const int*   idx = (const int*)d_in[0];
  const float* emb = (const float*)d_in[1];
  const float* pos = (const float*)d_in[2];
  const float* WQ1 = (const float*)d_in[3];
  const float* WK1 = (const float*)d_in[4];
  const float* WV1 = (const float*)d_in[5];
  const float* WQ2 = (const float*)d_in[6];
  const float* WK2 = (const float*)d_in[7];
  const float* b1  = (const float*)d_in[8];
  const float* b2  = (const float*)d_in[9];
  const float* bo  = (const float*)d_in[10];
  float* out = (float*)d_out;

  size_t off = 0;
  auto take = [&](size_t n) { void* p = (char*)d_ws + off; off += (n + 255) & ~(size_t)255; return p; };
  u16*   Pbf  = (u16*)take((size_t)SEQ * SEQ * 2);
  u16*   Wqk  = (u16*)take((size_t)SEQ * SEQ * 4);  // [WQ1bf ; WK1bf], 4096 x 2048
  u16*   Q1b  = (u16*)take((size_t)SEQ * SEQ * 2);
  u16*   K1b  = (u16*)take((size_t)SEQ * SEQ * 2);
  u16*   S1p  = (u16*)take((size_t)4 * NTRIL * 16384 * 2);  // packed bf16 split-K partials, ~17.8 MB
  // ---- zero-init region (zeroed in cvt_all seg 3): g, cnt1, rr, wv, cnt2 ----
  float* g    = (float*)take((size_t)BATCH * VOCAB * 4);
  float* cnt1 = (float*)take((size_t)BATCH * VOCAB * 4);
  float* rr   = (float*)take((size_t)BATCH * VOCAB * 4);  // rr & wv contiguous -> rw[16][V]
  float* wv   = (float*)take((size_t)BATCH * VOCAB * 4);
  float* cnt2 = (float*)take((size_t)BATCH * VOCAB * 4);
  // ---- plain scratch (fully overwritten) ----
  float* zl   = (float*)take((size_t)BATCH * VOCAB * 4);
  float* q2   = (float*)take((size_t)BATCH * VOCAB * 4);
  float* D    = (float*)take((size_t)VOCAB * 16 * 4);
  float* uu   = (float*)take((size_t)BATCH * SEQ * 4);
  float* vv   = (float*)take((size_t)BATCH * SEQ * 4);
  (void)wv;

  const int nz4 = 5 * BATCH * VOCAB / 4;  // 20480 float4s to zero (g..cnt2)

  // convert P, WQ1, WK1 to bf16 + zero the atomic-target region
  cvt_all<<<dim3(SEQ * SEQ / 4 / 256, 4), 256, 0, stream>>>(pos, WQ1, WK1, Pbf, Wqk, (float4*)g, nz4);

  // fused Q1|K1 GEMM: 512 blocks, BK=64 2-phase dbuf, XCD-chunked swizzle
  gemm_qk<<<512, 256, 0, stream>>>(Pbf, Wqk, Q1b, K1b);

  // S1 partials: tril tiles, split-K4, BK=32, bf16 packed stores
  gemm_s1<<<4 * NTRIL, 256, 0, stream>>>(Q1b, K1b, S1p);

  // softmax of row S-1 -> scatter cnt1[b,w]
  softmax_last<<<BATCH, 256, 0, stream>>>(S1p, b1, idx, cnt1);

  // g[b] = sum_w cnt1[b,w] emb[w,:]
  matvec_col<<<dim3(VOCAB / 256, 64), 256, 0, stream>>>(emb, cnt1, g, nullptr);

  // z_last[b] = E[b,S-1] + WV1 g[b];  q2[b] = WQ2 z_last[b]
  matvec_row<1><<<VOCAB / 4, 256, 0, stream>>>(WV1, g, zl, idx, emb);
  matvec_row<0><<<VOCAB / 4, 256, 0, stream>>>(WQ2, zl, q2, nullptr, nullptr);

  // rr[b] = WK2^T q2[b];  wv[b] = WV1^T rr[b]
  matvec_col<<<dim3(VOCAB / 256, 64), 256, 0, stream>>>(WK2, q2, rr, nullptr);
  matvec_col<<<dim3(VOCAB / 256, 64), 256, 0, stream>>>(WV1, rr, wv, nullptr);

  // D[w,j] = emb[w] . rw[j]  (j=0..7 -> rr, 8..15 -> wv); wave-per-word
  emb_dots16<<<VOCAB / 4, 256, 0, stream>>>(emb, rr, D);

  // uu[b,s] = D[idx[b,s], 8+b]
  gath_u<<<BATCH * SEQ / 256, 256, 0, stream>>>(idx, D, uu);

  // vv[b,s] = softmax_causal(row s) . u[b,:]  (longest rows first)
  sm_apply<<<SEQ, 256, 0, stream>>>(S1p, b1, uu, vv);

  // A2 softmax -> scatter cnt2 (also zeroes out)
  softmax2<<<BATCH, 256, 0, stream>>>(D, vv, idx, cnt2, b2, (float4*)out);

  // out[b] = beta_out * sum_w cnt2[b,w] emb[w,:]
  matvec_col<<<dim3(VOCAB / 256, 64), 256, 0, stream>>>(emb, cnt2, out, bo);
}